// Round 8
// baseline (38.240 us; speedup 1.0000x reference)
//
#include <hip/hip_runtime.h>
#include <math.h>

#define PP 9       // K*K
#define CAPS 32
#define PS 16
#define OH 15
#define HH 32
#define WW 32
#define LN_2PI 1.8378770664093453f

typedef float f32x2 __attribute__((ext_vector_type(2)));

__device__ __forceinline__ float frcp(float x) {
    float r;
    asm("v_rcp_f32 %0, %1" : "=v"(r) : "v"(x));
    return r;
}
__device__ __forceinline__ f32x2 splat2(float x) {
    f32x2 r; r.x = x; r.y = x; return r;
}
__device__ __forceinline__ f32x2 pkfma(f32x2 a, f32x2 b, f32x2 c) {
    return __builtin_elementwise_fma(a, b, c);  // -> v_pk_fma_f32 (gfx950 packed fp32)
}

// DPP helpers (VALU pipe): quad_perm xor1=0xB1, xor2=0x4E; row_ror:4=0x124, row_ror:8=0x128.
template <int CTRL>
__device__ __forceinline__ float dppf(float x) {
    int r = __builtin_amdgcn_update_dpp(0, __builtin_bit_cast(int, x), CTRL, 0xF, 0xF, true);
    return __builtin_bit_cast(float, r);
}
__device__ __forceinline__ float row_sum16(float x) {
    x += dppf<0xB1>(x);
    x += dppf<0x4E>(x);
    x += dppf<0x124>(x);
    x += dppf<0x128>(x);
    return x;
}
__device__ __forceinline__ float row_max16(float x) {
    x = fmaxf(x, dppf<0xB1>(x));
    x = fmaxf(x, dppf<0x4E>(x));
    x = fmaxf(x, dppf<0x124>(x));
    x = fmaxf(x, dppf<0x128>(x));
    return x;
}
// xor16 within each 32-lane group (and-mask 0x1F) -> halves (= the 2 sites)
// stay independent. PROVEN primitive (R3, 38.2us). permlane16_swap was tried
// twice (R5 asm, R6 builtin) and both times the allocator coalesced the two
// identical inputs into ONE register -> in-place row rotation -> 2*x[lane^16]
// instead of x + x[lane^16]. Do not retry with identical inputs.
__device__ __forceinline__ float swz_xor16(float x) {
    return __builtin_bit_cast(float,
        __builtin_amdgcn_ds_swizzle(__builtin_bit_cast(int, x), 0x401F));
}

// Layout (proven 38.1us): each 64-lane wave = TWO sites (32 lanes each),
// lane = s*32 + c; thread owns all 16 pose elems of capsule c of site s.
// All pose math packed f32x2 (v_pk_fma_f32); E-step phase-batched (R7).
//
// NEW vs R7 — attack the I$/sequencer, not the data path. Evidence: wall is
// insensitive to FETCH (R2 -50% -> nil), busy count (R3 -21% -> -4%), and
// cross-lane latency (R7 -> nil); but R2 absorbed 1.8x busy-work at LOWER
// wall when 4 phase-aligned waves shared one CU. Shared per-CU resource
// with that signature = instruction fetch. Fully-unrolled 3-trip EM loop
// ~= 32KB code = L1I size -> streaming thrash.
//  (1) #pragma unroll 1 on the EM loop: E-step and M-step each appear ONCE
//      (~2.5x code shrink, I$-resident). if(it>0) = one uniform s_cbranch.
//  (2) 256-thread blocks (4 waves = 8 consecutive sites): co-resident waves
//      run near phase-aligned -> 4x I$ line reuse (the R2 effect, without
//      split-PS's busy penalty).
// Per-wave instruction stream is bit-identical to R7's math.
__global__ __launch_bounds__(256, 2) void emcaps_kernel(
    const float* __restrict__ x,      // (32,32,32,32,16)
    const float* __restrict__ a,      // (32,32,32,32)
    const float* __restrict__ wgt,    // (9,32,4,4)
    const float* __restrict__ beta_u, // (32)
    const float* __restrict__ beta_a, // (32)
    float* __restrict__ out_mu,       // (32,15,15,32,16)
    float* __restrict__ out_a)        // (32,15,15,32)
{
    const int tid = threadIdx.x;
    const int wid = tid >> 6;       // wave within block (0..3)
    const int lane = tid & 63;
    const int s = lane >> 5;        // site within pair
    const int c = lane & 31;        // capsule

    const int site = blockIdx.x * 8 + wid * 2 + s;
    const int j = site % OH;
    const int t2 = site / OH;
    const int i = t2 % OH;
    const int b = t2 / OH;
    const int h0 = 2 * i, w0 = 2 * j;

    // ---- phase 1: all global loads issued back-to-back ----
    f32x2 v[PP][8];    // holds x now; overwritten with votes in phase 2
    float r[PP];
    #pragma unroll
    for (int k = 0; k < PP; ++k) {
        const int hh = h0 + k / 3, ww = w0 + k % 3;
        const size_t pix = (size_t)(b * HH + hh) * WW + ww;
        const float* xb = x + pix * (CAPS * PS) + c * PS;
        *(float4*)&v[k][0] = *(const float4*)xb;
        *(float4*)&v[k][2] = *(const float4*)(xb + 4);
        *(float4*)&v[k][4] = *(const float4*)(xb + 8);
        *(float4*)&v[k][6] = *(const float4*)(xb + 12);
        r[k] = a[pix * CAPS + c] * (1.f / 32.f);  // initial r (it0)
    }

    // ---- phase 2: votes in place (weights are L1-hot: 18 KB total) ----
    // pair m covers t=(2m,2m+1): x row idx 4*(m>>1)+q; weight pair w2[q*2+(m&1)].
    #pragma unroll
    for (int k = 0; k < PP; ++k) {
        float xt[PS];
        #pragma unroll
        for (int m = 0; m < 8; ++m) { xt[2 * m] = v[k][m].x; xt[2 * m + 1] = v[k][m].y; }
        f32x2 w2[8];
        const float* wb = wgt + k * (CAPS * PS) + c * PS;
        *(float4*)&w2[0] = *(const float4*)wb;
        *(float4*)&w2[2] = *(const float4*)(wb + 4);
        *(float4*)&w2[4] = *(const float4*)(wb + 8);
        *(float4*)&w2[6] = *(const float4*)(wb + 12);
        #pragma unroll
        for (int m = 0; m < 8; ++m) {
            f32x2 acc = splat2(0.f);
            #pragma unroll
            for (int q = 0; q < 4; ++q)
                acc = pkfma(splat2(xt[4 * (m >> 1) + q]), w2[q * 2 + (m & 1)], acc);
            v[k][m] = acc;
        }
    }

    const float bu = beta_u[c];
    const float ba = beta_a[c];
    const float eps = 1e-6f;
    const float lam = 1e-3f;

    f32x2 mu2[8], is22[8];   // is22 = 1/(2*sigma^2)
    float aoc = 0.f;
    float slgfull = 0.f;
    float r_sum;

    #pragma unroll 1   // CODE-SIZE: keep ONE copy of E-step + M-step in the binary
    for (int it = 0; it < 3; ++it) {
        if (it > 0) {
            // ---- E-step: phase-batched across the 9 independent k-chains ----
            const float addc = __logf(aoc) - slgfull - 8.f * LN_2PI;
            float lnk[PP], red[PP];
            #pragma unroll
            for (int k = 0; k < PP; ++k) {          // phase A: ln-posteriors
                f32x2 s2 = splat2(0.f);
                #pragma unroll
                for (int m = 0; m < 8; ++m) {
                    f32x2 d = v[k][m] - mu2[m];
                    s2 = pkfma(d * d, is22[m], s2);
                }
                lnk[k] = addc - (s2.x + s2.y);
            }
            #pragma unroll
            for (int k = 0; k < PP; ++k) red[k] = row_max16(lnk[k]);   // B: DPP maxes
            #pragma unroll
            for (int k = 0; k < PP; ++k)                                // C: 9 swizzles
                red[k] = fmaxf(red[k], swz_xor16(red[k]));              //    pipelined
            #pragma unroll
            for (int k = 0; k < PP; ++k) lnk[k] = __expf(lnk[k] - red[k]); // D: exps
            #pragma unroll
            for (int k = 0; k < PP; ++k) red[k] = row_sum16(lnk[k]);   // E: DPP sums
            #pragma unroll
            for (int k = 0; k < PP; ++k)                                // F: 9 swizzles
                red[k] += swz_xor16(red[k]);                            //    pipelined
            #pragma unroll
            for (int k = 0; k < PP; ++k) r[k] = lnk[k] * frcp(red[k]); // G: normalize
        }

        // ---- M-step: two-pass (numerically required) ----
        r_sum = 0.f;
        #pragma unroll
        for (int k = 0; k < PP; ++k) r_sum += r[k];
        const float invr = frcp(r_sum + eps);
        f32x2 rr[PP];
        #pragma unroll
        for (int k = 0; k < PP; ++k) { r[k] *= invr; rr[k] = splat2(r[k]); }

        #pragma unroll
        for (int m = 0; m < 8; ++m) {
            f32x2 acc = splat2(0.f);
            #pragma unroll
            for (int k = 0; k < PP; ++k) acc = pkfma(rr[k], v[k][m], acc);
            mu2[m] = acc;
        }
        float slg = 0.f;
        #pragma unroll
        for (int m = 0; m < 8; ++m) {
            f32x2 acc = splat2(0.f);
            #pragma unroll
            for (int k = 0; k < PP; ++k) {
                f32x2 d = v[k][m] - mu2[m];
                acc = pkfma(rr[k] * d, d, acc);
            }
            f32x2 sg = acc + splat2(eps);
            is22[m].x = frcp(2.f * sg.x);
            is22[m].y = frcp(2.f * sg.y);
            slg += 0.5f * __logf(sg.x * sg.y);   // = 0.5*(log sx + log sy)
        }
        slgfull = slg;
        const float ch = r_sum * (16.f * bu + slgfull);
        aoc = frcp(1.f + __expf(-lam * (ba - ch)));
    }

    // ---- outputs: each thread stores its 16 mu's (64B) + its a ----
    float* ob = out_mu + (size_t)site * (CAPS * PS) + c * PS;
    *(float4*)(ob + 0)  = *(float4*)&mu2[0];
    *(float4*)(ob + 4)  = *(float4*)&mu2[2];
    *(float4*)(ob + 8)  = *(float4*)&mu2[4];
    *(float4*)(ob + 12) = *(float4*)&mu2[6];
    out_a[(size_t)site * CAPS + c] = aoc;
}

extern "C" void kernel_launch(void* const* d_in, const int* in_sizes, int n_in,
                              void* d_out, int out_size, void* d_ws, size_t ws_size,
                              hipStream_t stream) {
    const float* x      = (const float*)d_in[0];
    const float* a      = (const float*)d_in[1];
    const float* wgt    = (const float*)d_in[2];
    const float* beta_u = (const float*)d_in[3];
    const float* beta_a = (const float*)d_in[4];

    float* out_mu = (float*)d_out;
    float* out_a  = (float*)d_out + (size_t)32 * OH * OH * CAPS * PS;  // 3,686,400

    const int n_sites = 32 * OH * OH;      // 7200
    const int n_blocks = n_sites / 8;      // 900 blocks x 4 waves (8 sites)
    emcaps_kernel<<<n_blocks, 256, 0, stream>>>(x, a, wgt, beta_u, beta_a, out_mu, out_a);
}